// Round 1
// baseline (4290.966 us; speedup 1.0000x reference)
//
#include <hip/hip_runtime.h>
#include <hip/hip_bf16.h>

#define BB 8
#define TT 512
#define KK 8
#define HH 128
#define G3 384
#define DIN 100
#define DG 50
#define NL 20

__device__ __forceinline__ float sigmf_(float x) { return 1.0f / (1.0f + expf(-x)); }

// ---------------- kernel 1a: g3x = x @ W_ih^T + b_lstm ; alphax = x @ Wa_ih^T + b_alpha
__global__ __launch_bounds__(512, 1)
void embed_gates_kernel(const int* __restrict__ wid, const int* __restrict__ bwid,
                        const float* __restrict__ wtab, const float* __restrict__ bwtab,
                        const float* __restrict__ Wih, const float* __restrict__ Waih,
                        const float* __restrict__ bl, const float* __restrict__ ba,
                        float* __restrict__ g3x, float* __restrict__ axo,
                        int c0, int CH)
{
    __shared__ float xs[8][104];
    const int tid = threadIdx.x;
    const int bpg = CH >> 3;
    const int b = blockIdx.x / bpg;
    const int tg = blockIdx.x % bpg;
    const int t0 = c0 + tg * 8;

    for (int idx = tid; idx < 800; idx += 512) {
        int tt = idx / 100;
        int c = idx - tt * 100;
        int t = t0 + tt;
        float v;
        if (c < 50) v = wtab[(long)wid[b * TT + t] * 50 + c];
        else        v = bwtab[(long)bwid[b * TT + t] * 50 + (c - 50)];
        xs[tt][c] = v;
    }
    __syncthreads();

    const int row = tid;
    float w[100];
    const float* wr;
    float bias;
    if (row < G3) { wr = Wih + (long)row * DIN; bias = bl[row]; }
    else          { wr = Waih + (long)(row - G3) * DIN; bias = ba[row - G3]; }
    const float4* wr4 = (const float4*)wr;
#pragma unroll
    for (int q = 0; q < 25; ++q) {
        float4 v = wr4[q];
        w[4*q] = v.x; w[4*q+1] = v.y; w[4*q+2] = v.z; w[4*q+3] = v.w;
    }
#pragma unroll 1
    for (int tt = 0; tt < 8; ++tt) {
        float a = bias;
#pragma unroll
        for (int c = 0; c < 100; ++c) a += w[c] * xs[tt][c];
        int lt = t0 - c0 + tt;
        if (row < G3) g3x[((long)b * CH + lt) * G3 + row] = a;
        else          axo[((long)b * CH + lt) * HH + (row - G3)] = a;
    }
}

// ---------------- kernel 1b: gwT[b][t][384][8] = Ww_ih @ gaz_emb + b_word
__global__ __launch_bounds__(384, 1)
void gaz_gates_kernel(const int* __restrict__ gids, const float* __restrict__ gtab,
                      const float* __restrict__ Wwih, const float* __restrict__ bw,
                      float* __restrict__ gwT, int c0, int CH)
{
    __shared__ float ges[64][52];
    const int tid = threadIdx.x;
    const int bpg = CH >> 3;
    const int b = blockIdx.x / bpg;
    const int tg = blockIdx.x % bpg;
    const int t0 = c0 + tg * 8;

    for (int idx = tid; idx < 64 * 50; idx += 384) {
        int p = idx / 50;
        int c = idx - p * 50;
        int tt = p >> 3, k = p & 7;
        int gid = gids[((long)(b * TT + t0 + tt)) * KK + k];
        ges[p][c] = gtab[(long)gid * DG + c];
    }
    __syncthreads();

    const int row = tid;
    float w[50];
    const float2* wr2 = (const float2*)(Wwih + (long)row * DG);
#pragma unroll
    for (int q = 0; q < 25; ++q) { float2 v = wr2[q]; w[2*q] = v.x; w[2*q+1] = v.y; }
    const float bias = bw[row];
    const int lt0 = t0 - c0;
#pragma unroll 1
    for (int p = 0; p < 64; ++p) {
        float a = bias;
#pragma unroll
        for (int c = 0; c < 50; ++c) a += w[c] * ges[p][c];
        int tt = p >> 3, k = p & 7;
        gwT[(((long)b * CH + lt0 + tt) * G3 + row) * KK + k] = a;
    }
}

// ---------------- kernel 2: sequential lattice scan, one block per batch
__global__ __launch_bounds__(512, 1)
void lattice_scan_kernel(const float* __restrict__ g3x, const float* __restrict__ axb,
                         const float* __restrict__ gwT, const int* __restrict__ gstarts,
                         const int* __restrict__ gmask,
                         const float* __restrict__ Whh, const float* __restrict__ Wwhh,
                         const float* __restrict__ Wahh,
                         float* __restrict__ hs, float* __restrict__ state,
                         int c0, int CH)
{
    __shared__ float cring[8][132];
    __shared__ float cwS[8][132];
    __shared__ float wwh[8][388];
    __shared__ float whh[G3];
    __shared__ float g3v[G3];
    __shared__ float axS[HH];
    __shared__ float hcur[HH];

    const int tid = threadIdx.x;
    const int b = blockIdx.x;
    const int ce = tid & 3;        // quad column-slice (phase C/E)
    const int rq = tid >> 2;       // 0..127  output row (phase C/E)
    const int kB = tid & 7;        // phase B gaz index
    const int r2 = tid >> 3;       // 0..63   phase B row base

    // register-resident weights: W2 = [W_hh ; Ww_hh]  (768 x 128), rotated col layout
    float WE[6][32];
    float WA[32];
    {
#pragma unroll
        for (int i = 0; i < 6; ++i) {
            int r = rq + 128 * i;
            const float* row = (r < G3) ? (Whh + (long)r * HH) : (Wwhh + (long)(r - G3) * HH);
#pragma unroll
            for (int g = 0; g < 8; ++g) {
                int off = 32 * ce + ((4 * g + 8 * ce) & 31);
                float4 v = *(const float4*)(row + off);
                WE[i][4*g] = v.x; WE[i][4*g+1] = v.y; WE[i][4*g+2] = v.z; WE[i][4*g+3] = v.w;
            }
        }
        const float* arow = Wahh + (long)rq * HH;
#pragma unroll
        for (int g = 0; g < 8; ++g) {
            int off = 32 * ce + ((4 * g + 8 * ce) & 31);
            float4 v = *(const float4*)(arow + off);
            WA[4*g] = v.x; WA[4*g+1] = v.y; WA[4*g+2] = v.z; WA[4*g+3] = v.w;
        }
    }

    float* st = state + (long)b * 4480;  // cring 1024 | wwh 3072 | whh 384
    if (c0 == 0) {
        for (int idx = tid; idx < 8 * 132; idx += 512) ((float*)cring)[idx] = 0.f;
        for (int idx = tid; idx < 8 * 388; idx += 512) ((float*)wwh)[idx] = 0.f;
        for (int idx = tid; idx < G3; idx += 512) whh[idx] = 0.f;
    } else {
        for (int idx = tid; idx < 1024; idx += 512) cring[idx >> 7][idx & 127] = st[idx];
        for (int idx = tid; idx < 3072; idx += 512) wwh[idx / 384][idx % 384] = st[1024 + idx];
        for (int idx = tid; idx < 384; idx += 512) whh[idx] = st[4096 + idx];
    }
    __syncthreads();

    for (int j = c0; j < c0 + CH; ++j) {
        const int lt = j - c0;
        // ---- Phase A: char gate pre-activations
        if (tid < G3) g3v[tid] = g3x[((long)b * CH + lt) * G3 + tid] + whh[tid];
        else          axS[tid - G3] = axb[((long)b * CH + lt) * HH + (tid - G3)];

        // ---- Phase B: word-LSTM cells (skip masked edges: exact, their weight is 0)
        const float* gw = gwT + ((long)(b * CH + lt)) * G3 * KK;
        const int base = (b * TT + j) * KK;
        const int s_ = gstarts[base + kB];
        const int m_ = gmask[base + kB];
        const bool valid = (m_ != 0);
        const bool hw_any = (__ballot(valid) != 0ull);
        if (valid) {
            const int slot = s_ & 7;
#pragma unroll
            for (int u = 0; u < 2; ++u) {
                int rr = r2 + 64 * u;
                float iw = gw[(rr) * KK + kB]       + wwh[slot][rr];
                float fw = gw[(rr + 128) * KK + kB] + wwh[slot][rr + 128];
                float gv = gw[(rr + 256) * KK + kB] + wwh[slot][rr + 256];
                float cs = cring[slot][rr];
                cwS[kB][rr] = sigmf_(fw) * cs + sigmf_(iw) * tanhf(gv);
            }
        }
        __syncthreads();

        // ---- Phase C: alpha = sigmoid(alphax + Wa_hh @ c_w), softmax-style aggregation
        const int* gm = gmask + base;
        float ax_v = axS[rq];
        float sumw = 0.f, sumwc = 0.f;
#pragma unroll 1
        for (int k = 0; k < 8; ++k) {
            if (gm[k] == 0) continue;   // block-uniform branch
            float acc = 0.f;
#pragma unroll
            for (int g = 0; g < 8; ++g) {
                int off = 32 * ce + ((4 * g + 8 * ce) & 31);
                const float* p = &cwS[k][off];
                acc += WA[4*g] * p[0] + WA[4*g+1] * p[1] + WA[4*g+2] * p[2] + WA[4*g+3] * p[3];
            }
            acc += __shfl_xor(acc, 1);
            acc += __shfl_xor(acc, 2);
            float a = sigmf_(ax_v + acc);
            float w = expf(a);
            sumw += w;
            sumwc += w * cwS[k][rq];
        }

        // ---- Phase D: char cell + merge
        float i_ = sigmf_(g3v[rq]);
        float o_ = sigmf_(g3v[rq + 128]);
        float g_ = tanhf(g3v[rq + 256]);
        float cprev = cring[(j - 1) & 7][rq];
        float wc = expf(i_);
        float csoft = (wc * g_ + sumwc) / (wc + sumw);
        float ccpl = (1.f - i_) * cprev + i_ * g_;
        float cn = hw_any ? csoft : ccpl;
        float hn = o_ * tanhf(cn);
        if (ce == 0) {
            cring[j & 7][rq] = cn;
            hcur[rq] = hn;
            hs[((long)b * CH + lt) * HH + rq] = hn;
        }
        __syncthreads();

        // ---- Phase E: produce W_hh@h (next char gates) and Ww_hh@h (future word edges)
        float accE[6] = {0.f, 0.f, 0.f, 0.f, 0.f, 0.f};
#pragma unroll
        for (int g = 0; g < 8; ++g) {
            int off = 32 * ce + ((4 * g + 8 * ce) & 31);
            const float4 v = *(const float4*)&hcur[off];
#pragma unroll
            for (int i = 0; i < 6; ++i)
                accE[i] += WE[i][4*g] * v.x + WE[i][4*g+1] * v.y + WE[i][4*g+2] * v.z + WE[i][4*g+3] * v.w;
        }
#pragma unroll
        for (int i = 0; i < 6; ++i) {
            float a = accE[i];
            a += __shfl_xor(a, 1);
            a += __shfl_xor(a, 2);
            if (ce == 0) {
                if (i < 3) whh[rq + 128 * i] = a;
                else       wwh[j & 7][rq + 128 * (i - 3)] = a;
            }
        }
        __syncthreads();
    }

    // persist state for next chunk
    for (int idx = tid; idx < 1024; idx += 512) st[idx] = cring[idx >> 7][idx & 127];
    for (int idx = tid; idx < 3072; idx += 512) st[1024 + idx] = wwh[idx / 384][idx % 384];
    for (int idx = tid; idx < 384; idx += 512) st[4096 + idx] = whh[idx];
}

// ---------------- kernel 3: logits + argmax (fwd==bwd, so fold W_tag halves)
__global__ __launch_bounds__(320, 1)
void tag_kernel(const float* __restrict__ hs, const float* __restrict__ Wtag,
                const float* __restrict__ btag, const int* __restrict__ maskp,
                int* __restrict__ out, int c0, int CH)
{
    __shared__ float ht[16][132];
    __shared__ float lg[16][20];
    const int tid = threadIdx.x;
    const int bpg = CH >> 4;
    const int b = blockIdx.x / bpg;
    const int tg = blockIdx.x % bpg;
    const int lt0 = tg * 16;

    for (int idx = tid; idx < 16 * 128; idx += 320)
        ht[idx >> 7][idx & 127] = hs[((long)b * CH + lt0 + (idx >> 7)) * HH + (idx & 127)];
    __syncthreads();

    {
        int tl = tid / 20, l = tid - tl * 20;
        float a = btag[l];
        const float* w0 = Wtag + (long)l * 256;
#pragma unroll
        for (int r = 0; r < 128; ++r) a += (w0[r] + w0[r + 128]) * ht[tl][r];
        lg[tl][l] = a;
    }
    __syncthreads();
    if (tid < 16) {
        float best = lg[tid][0];
        int bi = 0;
#pragma unroll
        for (int l = 1; l < NL; ++l) {
            float v = lg[tid][l];
            if (v > best) { best = v; bi = l; }   // first-max (np.argmax semantics)
        }
        int t = c0 + lt0 + tid;
        out[b * TT + t] = maskp[b * TT + t] * bi;
    }
}

extern "C" void kernel_launch(void* const* d_in, const int* in_sizes, int n_in,
                              void* d_out, int out_size, void* d_ws, size_t ws_size,
                              hipStream_t stream) {
    const int* word_inputs   = (const int*)d_in[0];
    const int* biword_inputs = (const int*)d_in[1];
    const int* gaz_word_ids  = (const int*)d_in[2];
    const int* gaz_starts    = (const int*)d_in[3];
    const int* gaz_mask      = (const int*)d_in[4];
    const int* maskp         = (const int*)d_in[5];
    const float* word_table   = (const float*)d_in[6];
    const float* biword_table = (const float*)d_in[7];
    const float* gaz_table    = (const float*)d_in[8];
    const float* W_ih   = (const float*)d_in[9];
    const float* W_hh   = (const float*)d_in[10];
    const float* b_lstm = (const float*)d_in[11];
    const float* Wa_ih  = (const float*)d_in[12];
    const float* Wa_hh  = (const float*)d_in[13];
    const float* b_alpha= (const float*)d_in[14];
    const float* Ww_ih  = (const float*)d_in[15];
    const float* Ww_hh  = (const float*)d_in[16];
    const float* b_word = (const float*)d_in[17];
    const float* W_tag  = (const float*)d_in[18];
    const float* b_tag  = (const float*)d_in[19];
    int* out = (int*)d_out;
    float* ws = (float*)d_ws;

    // choose T-chunk so workspace fits: bytes = 118784*CH + 143360
    int CH = 16;
    if      (ws_size >= 118784UL * 512 + 143360UL) CH = 512;
    else if (ws_size >= 118784UL * 128 + 143360UL) CH = 128;
    else if (ws_size >= 118784UL *  32 + 143360UL) CH = 32;

    float* g3x = ws;                               // B*CH*384
    float* axb = g3x + 8L * CH * 384;              // B*CH*128
    float* gwT = axb + 8L * CH * 128;              // B*CH*384*8
    float* hsb = gwT + 8L * CH * 3072;             // B*CH*128
    float* stb = hsb + 8L * CH * 128;              // B*4480

    for (int c0 = 0; c0 < TT; c0 += CH) {
        embed_gates_kernel<<<CH, 512, 0, stream>>>(word_inputs, biword_inputs,
                                                   word_table, biword_table,
                                                   W_ih, Wa_ih, b_lstm, b_alpha,
                                                   g3x, axb, c0, CH);
        gaz_gates_kernel<<<CH, 384, 0, stream>>>(gaz_word_ids, gaz_table,
                                                 Ww_ih, b_word, gwT, c0, CH);
        lattice_scan_kernel<<<BB, 512, 0, stream>>>(g3x, axb, gwT, gaz_starts, gaz_mask,
                                                    W_hh, Ww_hh, Wa_hh, hsb, stb, c0, CH);
        tag_kernel<<<CH / 2, 320, 0, stream>>>(hsb, W_tag, b_tag, maskp, out, c0, CH);
    }
}

// Round 2
// 3914.820 us; speedup vs baseline: 1.0961x; 1.0961x over previous
//
#include <hip/hip_runtime.h>
#include <hip/hip_bf16.h>

#define BB 8
#define TT 512
#define KK 8
#define HH 128
#define G3 384
#define DIN 100
#define DG 50
#define NL 20

__device__ __forceinline__ float sigmf_(float x) { return 1.0f / (1.0f + expf(-x)); }

// ---------------- kernel 1a: g3x = x @ W_ih^T + b_lstm ; alphax = x @ Wa_ih^T + b_alpha
__global__ __launch_bounds__(512, 1)
void embed_gates_kernel(const int* __restrict__ wid, const int* __restrict__ bwid,
                        const float* __restrict__ wtab, const float* __restrict__ bwtab,
                        const float* __restrict__ Wih, const float* __restrict__ Waih,
                        const float* __restrict__ bl, const float* __restrict__ ba,
                        float* __restrict__ g3x, float* __restrict__ axo,
                        int c0, int CH)
{
    __shared__ float xs[8][104];
    const int tid = threadIdx.x;
    const int bpg = CH >> 3;
    const int b = blockIdx.x / bpg;
    const int tg = blockIdx.x % bpg;
    const int t0 = c0 + tg * 8;

    for (int idx = tid; idx < 800; idx += 512) {
        int tt = idx / 100;
        int c = idx - tt * 100;
        int t = t0 + tt;
        float v;
        if (c < 50) v = wtab[(long)wid[b * TT + t] * 50 + c];
        else        v = bwtab[(long)bwid[b * TT + t] * 50 + (c - 50)];
        xs[tt][c] = v;
    }
    __syncthreads();

    const int row = tid;
    float w[100];
    const float* wr;
    float bias;
    if (row < G3) { wr = Wih + (long)row * DIN; bias = bl[row]; }
    else          { wr = Waih + (long)(row - G3) * DIN; bias = ba[row - G3]; }
    const float4* wr4 = (const float4*)wr;
#pragma unroll
    for (int q = 0; q < 25; ++q) {
        float4 v = wr4[q];
        w[4*q] = v.x; w[4*q+1] = v.y; w[4*q+2] = v.z; w[4*q+3] = v.w;
    }
#pragma unroll 1
    for (int tt = 0; tt < 8; ++tt) {
        float a = bias;
#pragma unroll
        for (int c = 0; c < 100; ++c) a += w[c] * xs[tt][c];
        int lt = t0 - c0 + tt;
        if (row < G3) g3x[((long)b * CH + lt) * G3 + row] = a;
        else          axo[((long)b * CH + lt) * HH + (row - G3)] = a;
    }
}

// ---------------- kernel 1b: gwT[b][t][384][8] = Ww_ih @ gaz_emb + b_word
__global__ __launch_bounds__(384, 1)
void gaz_gates_kernel(const int* __restrict__ gids, const float* __restrict__ gtab,
                      const float* __restrict__ Wwih, const float* __restrict__ bw,
                      float* __restrict__ gwT, int c0, int CH)
{
    __shared__ float ges[64][52];
    const int tid = threadIdx.x;
    const int bpg = CH >> 3;
    const int b = blockIdx.x / bpg;
    const int tg = blockIdx.x % bpg;
    const int t0 = c0 + tg * 8;

    for (int idx = tid; idx < 64 * 50; idx += 384) {
        int p = idx / 50;
        int c = idx - p * 50;
        int tt = p >> 3, k = p & 7;
        int gid = gids[((long)(b * TT + t0 + tt)) * KK + k];
        ges[p][c] = gtab[(long)gid * DG + c];
    }
    __syncthreads();

    const int row = tid;
    float w[50];
    const float2* wr2 = (const float2*)(Wwih + (long)row * DG);
#pragma unroll
    for (int q = 0; q < 25; ++q) { float2 v = wr2[q]; w[2*q] = v.x; w[2*q+1] = v.y; }
    const float bias = bw[row];
    const int lt0 = t0 - c0;
#pragma unroll 1
    for (int p = 0; p < 64; ++p) {
        float a = bias;
#pragma unroll
        for (int c = 0; c < 50; ++c) a += w[c] * ges[p][c];
        int tt = p >> 3, k = p & 7;
        gwT[(((long)b * CH + lt0 + tt) * G3 + row) * KK + k] = a;
    }
}

// ---------------- kernel 2: sequential lattice scan, one block per batch
__global__ __launch_bounds__(512, 1)
void lattice_scan_kernel(const float* __restrict__ g3x, const float* __restrict__ axb,
                         const float* __restrict__ gwT, const int* __restrict__ gstarts,
                         const int* __restrict__ gmask,
                         const float* __restrict__ Whh, const float* __restrict__ Wwhh,
                         const float* __restrict__ Wahh,
                         float* __restrict__ hs, float* __restrict__ state,
                         int c0, int CH)
{
    __shared__ float cring[8][132];
    __shared__ float cwS[8][132];
    __shared__ float wwh[8][388];
    __shared__ float whh[G3];
    __shared__ float g3v[G3];
    __shared__ float axS[HH];
    __shared__ float hcur[HH];

    const int tid = threadIdx.x;
    const int b = blockIdx.x;
    const int ce = tid & 3;        // quad column-slice (phase C/E)
    const int rq = tid >> 2;       // 0..127  output row (phase C/E)
    const int kB = tid & 7;        // phase B gaz index
    const int r2 = tid >> 3;       // 0..63   phase B row base

    // register-resident weights: W2 = [W_hh ; Ww_hh]  (768 x 128), rotated col layout
    float WE[6][32];
    float WA[32];
    {
#pragma unroll
        for (int i = 0; i < 6; ++i) {
            int r = rq + 128 * i;
            const float* row = (r < G3) ? (Whh + (long)r * HH) : (Wwhh + (long)(r - G3) * HH);
#pragma unroll
            for (int g = 0; g < 8; ++g) {
                int off = 32 * ce + ((4 * g + 8 * ce) & 31);
                float4 v = *(const float4*)(row + off);
                WE[i][4*g] = v.x; WE[i][4*g+1] = v.y; WE[i][4*g+2] = v.z; WE[i][4*g+3] = v.w;
            }
        }
        const float* arow = Wahh + (long)rq * HH;
#pragma unroll
        for (int g = 0; g < 8; ++g) {
            int off = 32 * ce + ((4 * g + 8 * ce) & 31);
            float4 v = *(const float4*)(arow + off);
            WA[4*g] = v.x; WA[4*g+1] = v.y; WA[4*g+2] = v.z; WA[4*g+3] = v.w;
        }
    }

    float* st = state + (long)b * 4480;  // cring 1024 | wwh 3072 | whh 384
    if (c0 == 0) {
        for (int idx = tid; idx < 8 * 132; idx += 512) ((float*)cring)[idx] = 0.f;
        for (int idx = tid; idx < 8 * 388; idx += 512) ((float*)wwh)[idx] = 0.f;
        for (int idx = tid; idx < G3; idx += 512) whh[idx] = 0.f;
    } else {
        for (int idx = tid; idx < 1024; idx += 512) cring[idx >> 7][idx & 127] = st[idx];
        for (int idx = tid; idx < 3072; idx += 512) wwh[idx / 384][idx % 384] = st[1024 + idx];
        for (int idx = tid; idx < 384; idx += 512) whh[idx] = st[4096 + idx];
    }
    __syncthreads();

    const long g3base = (long)b * CH * G3;
    const long axbase = (long)b * CH * HH;
    const long gwbase = (long)b * CH * 3072;

    // ---- prefetch registers for step c0
    float rA;
    float rgw[6];
    int rs, rm;
    {
        rA = (tid < G3) ? g3x[g3base + tid] : axb[axbase + (tid - G3)];
        const float* gw = gwT + gwbase;
#pragma unroll
        for (int u = 0; u < 2; ++u) {
            int rr = r2 + 64 * u;
            rgw[u*3+0] = gw[(rr)       * KK + kB];
            rgw[u*3+1] = gw[(rr + 128) * KK + kB];
            rgw[u*3+2] = gw[(rr + 256) * KK + kB];
        }
        int base = (b * TT + c0) * KK + kB;
        rs = gstarts[base];
        rm = gmask[base];
    }

    for (int j = c0; j < c0 + CH; ++j) {
        const int lt = j - c0;

        // ---- Phase A: consume prefetched activations
        if (tid < G3) g3v[tid] = rA + whh[tid];
        else          axS[tid - G3] = rA;

        // capture phase-B operands before re-using prefetch registers
        const bool valid = (rm != 0);
        const unsigned mask8 = (unsigned)(__ballot(valid) & 0xffull);
        const bool hw_any = (mask8 != 0u);
        const int slot = rs & 7;
        float t0_ = rgw[0], t1_ = rgw[1], t2_ = rgw[2];
        float t3_ = rgw[3], t4_ = rgw[4], t5_ = rgw[5];

        // ---- issue prefetch for step j+1 (latency hidden under this step's compute)
        if (lt + 1 < CH) {
            const int l2 = lt + 1;
            rA = (tid < G3) ? g3x[g3base + (long)l2 * G3 + tid]
                            : axb[axbase + (long)l2 * HH + (tid - G3)];
            const float* gw = gwT + gwbase + (long)l2 * 3072;
#pragma unroll
            for (int u = 0; u < 2; ++u) {
                int rr = r2 + 64 * u;
                rgw[u*3+0] = gw[(rr)       * KK + kB];
                rgw[u*3+1] = gw[(rr + 128) * KK + kB];
                rgw[u*3+2] = gw[(rr + 256) * KK + kB];
            }
            int base2 = (b * TT + j + 1) * KK + kB;
            rs = gstarts[base2];
            rm = gmask[base2];
        }

        // ---- Phase B: word-LSTM cells (masked edges skipped: weight is exactly 0)
        if (valid) {
            {
                float iw = t0_ + wwh[slot][r2];
                float fw = t1_ + wwh[slot][r2 + 128];
                float gv = t2_ + wwh[slot][r2 + 256];
                float cs = cring[slot][r2];
                cwS[kB][r2] = sigmf_(fw) * cs + sigmf_(iw) * tanhf(gv);
            }
            {
                int rr = r2 + 64;
                float iw = t3_ + wwh[slot][rr];
                float fw = t4_ + wwh[slot][rr + 128];
                float gv = t5_ + wwh[slot][rr + 256];
                float cs = cring[slot][rr];
                cwS[kB][rr] = sigmf_(fw) * cs + sigmf_(iw) * tanhf(gv);
            }
        }
        __syncthreads();

        // ---- Phase C: alpha = sigmoid(alphax + Wa_hh @ c_w), softmax-style aggregation
        float ax_v = axS[rq];
        float sumw = 0.f, sumwc = 0.f;
        unsigned mm = mask8;
#pragma unroll 1
        while (mm) {
            const int k = __ffs(mm) - 1;
            mm &= mm - 1;
            float acc = 0.f;
#pragma unroll
            for (int g = 0; g < 8; ++g) {
                int off = 32 * ce + ((4 * g + 8 * ce) & 31);
                const float* p = &cwS[k][off];
                acc += WA[4*g] * p[0] + WA[4*g+1] * p[1] + WA[4*g+2] * p[2] + WA[4*g+3] * p[3];
            }
            acc += __shfl_xor(acc, 1);
            acc += __shfl_xor(acc, 2);
            float a = sigmf_(ax_v + acc);
            float w = expf(a);
            sumw += w;
            sumwc += w * cwS[k][rq];
        }

        // ---- Phase D: char cell + merge
        float i_ = sigmf_(g3v[rq]);
        float o_ = sigmf_(g3v[rq + 128]);
        float g_ = tanhf(g3v[rq + 256]);
        float cprev = cring[(j - 1) & 7][rq];
        float wc = expf(i_);
        float csoft = (wc * g_ + sumwc) / (wc + sumw);
        float ccpl = (1.f - i_) * cprev + i_ * g_;
        float cn = hw_any ? csoft : ccpl;
        float hn = o_ * tanhf(cn);
        if (ce == 0) {
            cring[j & 7][rq] = cn;
            hcur[rq] = hn;
            hs[((long)b * CH + lt) * HH + rq] = hn;
        }
        __syncthreads();

        // ---- Phase E: produce W_hh@h (next char gates) and Ww_hh@h (future word edges)
        float accE[6] = {0.f, 0.f, 0.f, 0.f, 0.f, 0.f};
#pragma unroll
        for (int g = 0; g < 8; ++g) {
            int off = 32 * ce + ((4 * g + 8 * ce) & 31);
            const float4 v = *(const float4*)&hcur[off];
#pragma unroll
            for (int i = 0; i < 6; ++i)
                accE[i] += WE[i][4*g] * v.x + WE[i][4*g+1] * v.y + WE[i][4*g+2] * v.z + WE[i][4*g+3] * v.w;
        }
#pragma unroll
        for (int i = 0; i < 6; ++i) {
            float a = accE[i];
            a += __shfl_xor(a, 1);
            a += __shfl_xor(a, 2);
            if (ce == 0) {
                if (i < 3) whh[rq + 128 * i] = a;
                else       wwh[j & 7][rq + 128 * (i - 3)] = a;
            }
        }
        __syncthreads();
    }

    // persist state for next chunk
    for (int idx = tid; idx < 1024; idx += 512) st[idx] = cring[idx >> 7][idx & 127];
    for (int idx = tid; idx < 3072; idx += 512) st[1024 + idx] = wwh[idx / 384][idx % 384];
    for (int idx = tid; idx < 384; idx += 512) st[4096 + idx] = whh[idx];
}

// ---------------- kernel 3: logits + argmax (fwd==bwd, so fold W_tag halves)
__global__ __launch_bounds__(320, 1)
void tag_kernel(const float* __restrict__ hs, const float* __restrict__ Wtag,
                const float* __restrict__ btag, const int* __restrict__ maskp,
                int* __restrict__ out, int c0, int CH)
{
    __shared__ float ht[16][132];
    __shared__ float lg[16][20];
    const int tid = threadIdx.x;
    const int bpg = CH >> 4;
    const int b = blockIdx.x / bpg;
    const int tg = blockIdx.x % bpg;
    const int lt0 = tg * 16;

    for (int idx = tid; idx < 16 * 128; idx += 320)
        ht[idx >> 7][idx & 127] = hs[((long)b * CH + lt0 + (idx >> 7)) * HH + (idx & 127)];
    __syncthreads();

    {
        int tl = tid / 20, l = tid - tl * 20;
        float a = btag[l];
        const float* w0 = Wtag + (long)l * 256;
#pragma unroll
        for (int r = 0; r < 128; ++r) a += (w0[r] + w0[r + 128]) * ht[tl][r];
        lg[tl][l] = a;
    }
    __syncthreads();
    if (tid < 16) {
        float best = lg[tid][0];
        int bi = 0;
#pragma unroll
        for (int l = 1; l < NL; ++l) {
            float v = lg[tid][l];
            if (v > best) { best = v; bi = l; }   // first-max (np.argmax semantics)
        }
        int t = c0 + lt0 + tid;
        out[b * TT + t] = maskp[b * TT + t] * bi;
    }
}

extern "C" void kernel_launch(void* const* d_in, const int* in_sizes, int n_in,
                              void* d_out, int out_size, void* d_ws, size_t ws_size,
                              hipStream_t stream) {
    const int* word_inputs   = (const int*)d_in[0];
    const int* biword_inputs = (const int*)d_in[1];
    const int* gaz_word_ids  = (const int*)d_in[2];
    const int* gaz_starts    = (const int*)d_in[3];
    const int* gaz_mask      = (const int*)d_in[4];
    const int* maskp         = (const int*)d_in[5];
    const float* word_table   = (const float*)d_in[6];
    const float* biword_table = (const float*)d_in[7];
    const float* gaz_table    = (const float*)d_in[8];
    const float* W_ih   = (const float*)d_in[9];
    const float* W_hh   = (const float*)d_in[10];
    const float* b_lstm = (const float*)d_in[11];
    const float* Wa_ih  = (const float*)d_in[12];
    const float* Wa_hh  = (const float*)d_in[13];
    const float* b_alpha= (const float*)d_in[14];
    const float* Ww_ih  = (const float*)d_in[15];
    const float* Ww_hh  = (const float*)d_in[16];
    const float* b_word = (const float*)d_in[17];
    const float* W_tag  = (const float*)d_in[18];
    const float* b_tag  = (const float*)d_in[19];
    int* out = (int*)d_out;
    float* ws = (float*)d_ws;

    // choose T-chunk so workspace fits: bytes = 118784*CH + 143360
    int CH = 16;
    if      (ws_size >= 118784UL * 512 + 143360UL) CH = 512;
    else if (ws_size >= 118784UL * 128 + 143360UL) CH = 128;
    else if (ws_size >= 118784UL *  32 + 143360UL) CH = 32;

    float* g3x = ws;                               // B*CH*384
    float* axb = g3x + 8L * CH * 384;              // B*CH*128
    float* gwT = axb + 8L * CH * 128;              // B*CH*384*8
    float* hsb = gwT + 8L * CH * 3072;             // B*CH*128
    float* stb = hsb + 8L * CH * 128;              // B*4480

    for (int c0 = 0; c0 < TT; c0 += CH) {
        embed_gates_kernel<<<CH, 512, 0, stream>>>(word_inputs, biword_inputs,
                                                   word_table, biword_table,
                                                   W_ih, Wa_ih, b_lstm, b_alpha,
                                                   g3x, axb, c0, CH);
        gaz_gates_kernel<<<CH, 384, 0, stream>>>(gaz_word_ids, gaz_table,
                                                 Ww_ih, b_word, gwT, c0, CH);
        lattice_scan_kernel<<<BB, 512, 0, stream>>>(g3x, axb, gwT, gaz_starts, gaz_mask,
                                                    W_hh, Ww_hh, Wa_hh, hsb, stb, c0, CH);
        tag_kernel<<<CH / 2, 320, 0, stream>>>(hsb, W_tag, b_tag, maskp, out, c0, CH);
    }
}